// Round 2
// baseline (358.488 us; speedup 1.0000x reference)
//
#include <hip/hip_runtime.h>

typedef unsigned short u16;
typedef unsigned int u32;
typedef __bf16 bf16x8 __attribute__((ext_vector_type(8)));
typedef float floatx4 __attribute__((ext_vector_type(4)));

#define AS1 __attribute__((address_space(1)))
#define AS3 __attribute__((address_space(3)))

__device__ __forceinline__ u16 f2bf(float f) {
    union { float f; u32 u; } a; a.f = f;
    u32 u = a.u;
    u32 r = (u + 0x7fffu + ((u >> 16) & 1u)) >> 16;
    return (u16)r;
}
__device__ __forceinline__ float bf2f(u16 h) {
    union { u32 u; float f; } a; a.u = ((u32)h) << 16; return a.f;
}

// ---------------- fp32 -> bf16 cast, 4 elems/thread ----------------
__global__ void k_f2b(const float* __restrict__ in, u16* __restrict__ out, int n4) {
    int i = blockIdx.x * blockDim.x + threadIdx.x;
    if (i >= n4) return;
    float4 v = reinterpret_cast<const float4*>(in)[i];
    u32 lo = (u32)f2bf(v.x) | ((u32)f2bf(v.y) << 16);
    u32 hi = (u32)f2bf(v.z) | ((u32)f2bf(v.w) << 16);
    reinterpret_cast<uint2*>(out)[i] = make_uint2(lo, hi);
}

// ---------------- RoPE tables: cos/sin [S][64], emb = concat(freqs,freqs) ----------------
__global__ void k_rope_tab(float* __restrict__ ct, float* __restrict__ st) {
    int i = blockIdx.x * blockDim.x + threadIdx.x; // 2048*64
    if (i >= 2048 * 64) return;
    int s = i >> 6, d = i & 63;
    float inv = powf(10000.f, -(float)(d & 31) * (1.f / 32.f));
    float ang = (float)s * inv;
    ct[i] = cosf(ang);
    st[i] = sinf(ang);
}

// ---------------- RoPE in-place on q,k bf16 [B][S][H*64]; pairs (2i,2i+1) ----------------
__global__ void k_rope_apply(u16* __restrict__ q, u16* __restrict__ k,
                             const float* __restrict__ ct, const float* __restrict__ st) {
    int t = blockIdx.x * blockDim.x + threadIdx.x; // 2^21 = B*S*H*32
    int d2 = t & 31; int h = (t >> 5) & 15; int s = (t >> 9) & 2047; int b = t >> 20;
    int d0 = d2 * 2;
    int base = ((b * 2048 + s) * 1024) + h * 64 + d0;
    int tb = s * 64 + d0;
    float c0 = ct[tb], c1 = ct[tb + 1], s0 = st[tb], s1 = st[tb + 1];
    u32 qv = *reinterpret_cast<u32*>(q + base);
    float q0 = bf2f((u16)qv), q1 = bf2f((u16)(qv >> 16));
    float r0 = q0 * c0 - q1 * s0;
    float r1 = q1 * c1 + q0 * s1;
    *reinterpret_cast<u32*>(q + base) = (u32)f2bf(r0) | ((u32)f2bf(r1) << 16);
    u32 kv = *reinterpret_cast<u32*>(k + base);
    float k0 = bf2f((u16)kv), k1 = bf2f((u16)(kv >> 16));
    float t0 = k0 * c0 - k1 * s0;
    float t1 = k1 * c1 + k0 * s1;
    *reinterpret_cast<u32*>(k + base) = (u32)f2bf(t0) | ((u32)f2bf(t1) << 16);
}

// ---------------- Vt ones/zero fill: rows 64..79 of each [bh][80][2048] ----------------
__global__ void k_vfill(u32* __restrict__ vt32) {
    int j = blockIdx.x * blockDim.x + threadIdx.x; // 32*16*1024
    if (j >= 32 * 16 * 1024) return;
    int bh = j >> 14; int r = j & 16383; int dd = r >> 10; int su = r & 1023;
    vt32[(((bh * 80) + 64 + dd) << 10) + su] = (dd == 0) ? 0x3F803F80u : 0u;
}

// ---------------- fused QKV GEMM: z=0->Q, z=1->K (bf16 rowmajor), z=2->V (transposed [bh][80][S]) --
__global__ __launch_bounds__(256) void k_gemm_qkv(const u16* __restrict__ A,
        const u16* __restrict__ Wq, const u16* __restrict__ Wk, const u16* __restrict__ Wv,
        const float* __restrict__ Bq, const float* __restrict__ Bk, const float* __restrict__ Bv,
        u16* __restrict__ Oq, u16* __restrict__ Ok, u16* __restrict__ Vt) {
    __shared__ __attribute__((aligned(16))) u16 Alds[128 * 32];
    __shared__ __attribute__((aligned(16))) u16 Blds[128 * 32];
    const int z = blockIdx.z;
    const u16* __restrict__ W = (z == 0) ? Wq : (z == 1) ? Wk : Wv;
    const float* __restrict__ bias = (z == 0) ? Bq : (z == 1) ? Bk : Bv;
    const int tid = threadIdx.x;
    const int w = tid >> 6, lane = tid & 63;
    const int wr = w >> 1, wc = w & 1;
    const int c = lane & 15, g = lane >> 4;
    const int m0 = blockIdx.y * 128, n0 = blockIdx.x * 128;
    const int K = 1024, N = 1024;

    floatx4 acc[4][4] = {};
    const int srow = lane >> 2;
    const int skc = (lane & 3) * 8;

    for (int k0 = 0; k0 < K; k0 += 32) {
        #pragma unroll
        for (int ch = 0; ch < 2; ch++) {
            int cc = w + ch * 4;
            const u16* ga = A + (size_t)(m0 + cc * 16 + srow) * K + k0 + skc;
            const u16* gb = W + (size_t)(n0 + cc * 16 + srow) * K + k0 + skc;
            __builtin_amdgcn_global_load_lds((AS1 void*)(ga), (AS3 void*)(Alds + cc * 512), 16, 0, 0);
            __builtin_amdgcn_global_load_lds((AS1 void*)(gb), (AS3 void*)(Blds + cc * 512), 16, 0, 0);
        }
        __syncthreads();
        bf16x8 af[4], bfr[4];
        #pragma unroll
        for (int mi = 0; mi < 4; mi++)
            af[mi] = *reinterpret_cast<const bf16x8*>(Alds + (wr * 64 + mi * 16 + c) * 32 + g * 8);
        #pragma unroll
        for (int ni = 0; ni < 4; ni++)
            bfr[ni] = *reinterpret_cast<const bf16x8*>(Blds + (wc * 64 + ni * 16 + c) * 32 + g * 8);
        #pragma unroll
        for (int mi = 0; mi < 4; mi++)
            #pragma unroll
            for (int ni = 0; ni < 4; ni++)
                acc[mi][ni] = __builtin_amdgcn_mfma_f32_16x16x32_bf16(af[mi], bfr[ni], acc[mi][ni], 0, 0, 0);
        __syncthreads();
    }

    if (z < 2) {
        u16* __restrict__ Cout = (z == 0) ? Oq : Ok;
        #pragma unroll
        for (int ni = 0; ni < 4; ni++) {
            int col = n0 + wc * 64 + ni * 16 + c;
            float bv = bias[col];
            #pragma unroll
            for (int mi = 0; mi < 4; mi++)
                #pragma unroll
                for (int i = 0; i < 4; i++) {
                    int row = m0 + wr * 64 + mi * 16 + g * 4 + i;
                    Cout[(size_t)row * N + col] = f2bf(acc[mi][ni][i] + bv);
                }
        }
    } else {
        #pragma unroll
        for (int ni = 0; ni < 4; ni++) {
            int col = n0 + wc * 64 + ni * 16 + c;
            float bv = bias[col];
            int hh = col >> 6, d = col & 63;
            #pragma unroll
            for (int mi = 0; mi < 4; mi++) {
                int row0 = m0 + wr * 64 + mi * 16 + g * 4;
                int bb = row0 >> 11, s = row0 & 2047;
                u32 lo = (u32)f2bf(acc[mi][ni][0] + bv) | ((u32)f2bf(acc[mi][ni][1] + bv) << 16);
                u32 hi = (u32)f2bf(acc[mi][ni][2] + bv) | ((u32)f2bf(acc[mi][ni][3] + bv) << 16);
                size_t idx = ((size_t)((bb * 16 + hh) * 80 + d)) * 2048 + s;
                *reinterpret_cast<uint2*>(Vt + idx) = make_uint2(lo, hi);
            }
        }
    }
}

// ---------------- output GEMM: C = A @ W^T + bias, fp32 out ----------------
__global__ __launch_bounds__(256) void k_gemm_f32(const u16* __restrict__ A, const u16* __restrict__ W,
                                                  const float* __restrict__ bias, float* __restrict__ Cout) {
    __shared__ __attribute__((aligned(16))) u16 Alds[128 * 32];
    __shared__ __attribute__((aligned(16))) u16 Blds[128 * 32];
    const int tid = threadIdx.x;
    const int w = tid >> 6, lane = tid & 63;
    const int wr = w >> 1, wc = w & 1;
    const int c = lane & 15, g = lane >> 4;
    const int m0 = blockIdx.y * 128, n0 = blockIdx.x * 128;
    const int K = 1024, N = 1024;

    floatx4 acc[4][4] = {};
    const int srow = lane >> 2;
    const int skc = (lane & 3) * 8;

    for (int k0 = 0; k0 < K; k0 += 32) {
        #pragma unroll
        for (int ch = 0; ch < 2; ch++) {
            int cc = w + ch * 4;
            const u16* ga = A + (size_t)(m0 + cc * 16 + srow) * K + k0 + skc;
            const u16* gb = W + (size_t)(n0 + cc * 16 + srow) * K + k0 + skc;
            __builtin_amdgcn_global_load_lds((AS1 void*)(ga), (AS3 void*)(Alds + cc * 512), 16, 0, 0);
            __builtin_amdgcn_global_load_lds((AS1 void*)(gb), (AS3 void*)(Blds + cc * 512), 16, 0, 0);
        }
        __syncthreads();
        bf16x8 af[4], bfr[4];
        #pragma unroll
        for (int mi = 0; mi < 4; mi++)
            af[mi] = *reinterpret_cast<const bf16x8*>(Alds + (wr * 64 + mi * 16 + c) * 32 + g * 8);
        #pragma unroll
        for (int ni = 0; ni < 4; ni++)
            bfr[ni] = *reinterpret_cast<const bf16x8*>(Blds + (wc * 64 + ni * 16 + c) * 32 + g * 8);
        #pragma unroll
        for (int mi = 0; mi < 4; mi++)
            #pragma unroll
            for (int ni = 0; ni < 4; ni++)
                acc[mi][ni] = __builtin_amdgcn_mfma_f32_16x16x32_bf16(af[mi], bfr[ni], acc[mi][ni], 0, 0, 0);
        __syncthreads();
    }

    #pragma unroll
    for (int ni = 0; ni < 4; ni++) {
        int col = n0 + wc * 64 + ni * 16 + c;
        float bv = bias[col];
        #pragma unroll
        for (int mi = 0; mi < 4; mi++)
            #pragma unroll
            for (int i = 0; i < 4; i++) {
                int row = m0 + wr * 64 + mi * 16 + g * 4 + i;
                Cout[(size_t)row * N + col] = acc[mi][ni][i] + bv;
            }
    }
}

// ---------------- Flash attention, causal. 1 wave/block, 16 q-rows/wave, KV tile 32.
// Q,K bf16 [B][S][1024]; Vt bf16 [bh][80][2048] (row 64 = ones, 65..79 zero); O bf16 [B][S][1024].
__global__ __launch_bounds__(64) void k_attn(const u16* __restrict__ Q, const u16* __restrict__ K,
                                             const u16* __restrict__ Vt, u16* __restrict__ O) {
    __shared__ __attribute__((aligned(16))) u16 Plds[16 * 48];
    const int lane = threadIdx.x & 63;
    const int c = lane & 15, g = lane >> 4;
    const int bh = blockIdx.y;
    const int b = bh >> 4, h = bh & 15;
    const int q0 = ((int)gridDim.x - 1 - (int)blockIdx.x) * 16; // heavy-first
    const int rowb = b * 2048, colb = h * 64;
    const u16* __restrict__ Vb = Vt + (size_t)bh * 80 * 2048;

    bf16x8 qf[2];
    #pragma unroll
    for (int db = 0; db < 2; db++)
        qf[db] = *reinterpret_cast<const bf16x8*>(Q + (size_t)(rowb + q0 + c) * 1024 + colb + g * 8 + db * 32);

    const float SC = 0.125f * 1.44269504088896f; // scale * log2(e)
    float m[4];
    floatx4 acc[5] = {};
    #pragma unroll
    for (int i = 0; i < 4; i++) m[i] = -1e30f;

    const int nt = (q0 + 47) >> 5;
    for (int t = 0; t < nt; t++) {
        const int kv0 = t * 32;
        floatx4 s4[2] = {};
        #pragma unroll
        for (int cb = 0; cb < 2; cb++)
            #pragma unroll
            for (int db = 0; db < 2; db++) {
                bf16x8 kf = *reinterpret_cast<const bf16x8*>(
                    K + (size_t)(rowb + kv0 + cb * 16 + c) * 1024 + colb + g * 8 + db * 32);
                s4[cb] = __builtin_amdgcn_mfma_f32_16x16x32_bf16(qf[db], kf, s4[cb], 0, 0, 0);
            }
        bf16x8 vf[5];
        #pragma unroll
        for (int vb = 0; vb < 5; vb++)
            vf[vb] = *reinterpret_cast<const bf16x8*>(Vb + (size_t)(vb * 16 + c) * 2048 + kv0 + g * 8);

        float p[2][4];
        const bool need_mask = (kv0 + 31 > q0);
        #pragma unroll
        for (int cb = 0; cb < 2; cb++)
            #pragma unroll
            for (int i = 0; i < 4; i++) {
                float sv = s4[cb][i] * SC;
                if (need_mask && (kv0 + cb * 16 + c > q0 + g * 4 + i)) sv = -1e30f;
                p[cb][i] = sv;
            }
        #pragma unroll
        for (int i = 0; i < 4; i++) {
            float rm = fmaxf(p[0][i], p[1][i]);
            #pragma unroll
            for (int off = 1; off < 16; off <<= 1)
                rm = fmaxf(rm, __shfl_xor(rm, off));
            float mn = fmaxf(m[i], rm);
            float corr = exp2f(m[i] - mn);
            m[i] = mn;
            p[0][i] = exp2f(p[0][i] - mn);
            p[1][i] = exp2f(p[1][i] - mn);
            #pragma unroll
            for (int vb = 0; vb < 5; vb++)
                acc[vb][i] *= corr;
        }
        // P (C-layout) -> LDS -> A-layout fragment
        #pragma unroll
        for (int cb = 0; cb < 2; cb++)
            #pragma unroll
            for (int i = 0; i < 4; i++)
                Plds[(g * 4 + i) * 48 + cb * 16 + c] = f2bf(p[cb][i]);
        asm volatile("s_waitcnt lgkmcnt(0)" ::: "memory");
        bf16x8 pf = *reinterpret_cast<const bf16x8*>(&Plds[c * 48 + g * 8]);
        #pragma unroll
        for (int vb = 0; vb < 5; vb++)
            acc[vb] = __builtin_amdgcn_mfma_f32_16x16x32_bf16(pf, vf[vb], acc[vb], 0, 0, 0);
        asm volatile("" ::: "memory"); // keep next-iter ds_writes after this iter's ds_read
    }
    #pragma unroll
    for (int i = 0; i < 4; i++) {
        float ls = __shfl(acc[4][i], g << 4); // column 0 of sum block
        float inv = 1.f / ls;
        #pragma unroll
        for (int vb = 0; vb < 4; vb++)
            O[(size_t)(rowb + q0 + g * 4 + i) * 1024 + colb + vb * 16 + c] = f2bf(acc[vb][i] * inv);
    }
}

extern "C" void kernel_launch(void* const* d_in, const int* in_sizes, int n_in,
                              void* d_out, int out_size, void* d_ws, size_t ws_size,
                              hipStream_t stream) {
    const float* x  = (const float*)d_in[0];
    const float* wq = (const float*)d_in[1];
    const float* bq = (const float*)d_in[2];
    const float* wk = (const float*)d_in[3];
    const float* bk = (const float*)d_in[4];
    const float* wv = (const float*)d_in[5];
    const float* bv = (const float*)d_in[6];
    const float* wo = (const float*)d_in[7];
    const float* bo = (const float*)d_in[8];

    char* ws = (char*)d_ws;
    u16* xb  = (u16*)(ws);                      // 8 MiB [4096][1024]
    u16* wqb = (u16*)(ws + (8ull  << 20));      // 2 MiB each
    u16* wkb = (u16*)(ws + (10ull << 20));
    u16* wvb = (u16*)(ws + (12ull << 20));
    u16* wob = (u16*)(ws + (14ull << 20));
    u16* qg  = (u16*)(ws + (16ull << 20));      // 8 MiB
    u16* kg  = (u16*)(ws + (24ull << 20));      // 8 MiB
    u16* vt  = (u16*)(ws + (32ull << 20));      // 10 MiB [32][80][2048]
    u16* og  = (u16*)(ws + (42ull << 20));      // 8 MiB
    float* ct = (float*)(ws + (50ull << 20));   // 512 KiB
    float* st = (float*)(ws + (51ull << 20));   // 512 KiB (uses first 512K)

    k_f2b<<<4096, 256, 0, stream>>>(x,  xb,  1048576);
    k_f2b<<<1024, 256, 0, stream>>>(wq, wqb, 262144);
    k_f2b<<<1024, 256, 0, stream>>>(wk, wkb, 262144);
    k_f2b<<<1024, 256, 0, stream>>>(wv, wvb, 262144);
    k_f2b<<<1024, 256, 0, stream>>>(wo, wob, 262144);
    k_rope_tab<<<512, 256, 0, stream>>>(ct, st);
    k_vfill<<<2048, 256, 0, stream>>>((u32*)vt);

    dim3 gq(8, 32, 3);
    k_gemm_qkv<<<gq, 256, 0, stream>>>(xb, wqb, wkb, wvb, bq, bk, bv, qg, kg, vt);

    k_rope_apply<<<8192, 256, 0, stream>>>(qg, kg, ct, st);

    dim3 ga(128, 32);
    k_attn<<<ga, 64, 0, stream>>>(qg, kg, vt, og);

    k_gemm_f32<<<dim3(8, 32), 256, 0, stream>>>(og, wob, bo, (float*)d_out);
}

// Round 3
// 195.221 us; speedup vs baseline: 1.8363x; 1.8363x over previous
//
#include <hip/hip_runtime.h>

typedef unsigned short u16;
typedef unsigned int u32;
typedef __bf16 bf16x8 __attribute__((ext_vector_type(8)));
typedef float floatx4 __attribute__((ext_vector_type(4)));

#define AS1 __attribute__((address_space(1)))
#define AS3 __attribute__((address_space(3)))

__device__ __forceinline__ u16 f2bf(float f) {
    union { float f; u32 u; } a; a.f = f;
    u32 u = a.u;
    u32 r = (u + 0x7fffu + ((u >> 16) & 1u)) >> 16;
    return (u16)r;
}
__device__ __forceinline__ float bf2f(u16 h) {
    union { u32 u; float f; } a; a.u = ((u32)h) << 16; return a.f;
}

// ---------------- fp32 -> bf16 cast, 4 elems/thread ----------------
__global__ void k_f2b(const float* __restrict__ in, u16* __restrict__ out, int n4) {
    int i = blockIdx.x * blockDim.x + threadIdx.x;
    if (i >= n4) return;
    float4 v = reinterpret_cast<const float4*>(in)[i];
    u32 lo = (u32)f2bf(v.x) | ((u32)f2bf(v.y) << 16);
    u32 hi = (u32)f2bf(v.z) | ((u32)f2bf(v.w) << 16);
    reinterpret_cast<uint2*>(out)[i] = make_uint2(lo, hi);
}

// ---------------- RoPE tables ----------------
__global__ void k_rope_tab(float* __restrict__ ct, float* __restrict__ st) {
    int i = blockIdx.x * blockDim.x + threadIdx.x; // 2048*64
    if (i >= 2048 * 64) return;
    int s = i >> 6, d = i & 63;
    float inv = powf(10000.f, -(float)(d & 31) * (1.f / 32.f));
    float ang = (float)s * inv;
    ct[i] = cosf(ang);
    st[i] = sinf(ang);
}

// ---------------- RoPE in-place on q,k ----------------
__global__ void k_rope_apply(u16* __restrict__ q, u16* __restrict__ k,
                             const float* __restrict__ ct, const float* __restrict__ st) {
    int t = blockIdx.x * blockDim.x + threadIdx.x;
    int d2 = t & 31; int h = (t >> 5) & 15; int s = (t >> 9) & 2047; int b = t >> 20;
    int d0 = d2 * 2;
    int base = ((b * 2048 + s) * 1024) + h * 64 + d0;
    int tb = s * 64 + d0;
    float c0 = ct[tb], c1 = ct[tb + 1], s0 = st[tb], s1 = st[tb + 1];
    u32 qv = *reinterpret_cast<u32*>(q + base);
    float q0 = bf2f((u16)qv), q1 = bf2f((u16)(qv >> 16));
    float r0 = q0 * c0 - q1 * s0;
    float r1 = q1 * c1 + q0 * s1;
    *reinterpret_cast<u32*>(q + base) = (u32)f2bf(r0) | ((u32)f2bf(r1) << 16);
    u32 kv = *reinterpret_cast<u32*>(k + base);
    float k0 = bf2f((u16)kv), k1 = bf2f((u16)(kv >> 16));
    float t0 = k0 * c0 - k1 * s0;
    float t1 = k1 * c1 + k0 * s1;
    *reinterpret_cast<u32*>(k + base) = (u32)f2bf(t0) | ((u32)f2bf(t1) << 16);
}

// ---------------- fused QKV GEMM: z=0->Q, z=1->K rowmajor; z=2->V transposed [bh][64][S] ----
__global__ __launch_bounds__(256) void k_gemm_qkv(const u16* __restrict__ A,
        const u16* __restrict__ Wq, const u16* __restrict__ Wk, const u16* __restrict__ Wv,
        const float* __restrict__ Bq, const float* __restrict__ Bk, const float* __restrict__ Bv,
        u16* __restrict__ Oq, u16* __restrict__ Ok, u16* __restrict__ Vt) {
    __shared__ __attribute__((aligned(16))) u16 Alds[128 * 32];
    __shared__ __attribute__((aligned(16))) u16 Blds[128 * 32];
    const int z = blockIdx.z;
    const u16* __restrict__ W = (z == 0) ? Wq : (z == 1) ? Wk : Wv;
    const float* __restrict__ bias = (z == 0) ? Bq : (z == 1) ? Bk : Bv;
    const int tid = threadIdx.x;
    const int w = tid >> 6, lane = tid & 63;
    const int wr = w >> 1, wc = w & 1;
    const int c = lane & 15, g = lane >> 4;
    const int m0 = blockIdx.y * 128, n0 = blockIdx.x * 128;
    const int K = 1024, N = 1024;

    floatx4 acc[4][4] = {};
    const int srow = lane >> 2;
    const int skc = (lane & 3) * 8;

    for (int k0 = 0; k0 < K; k0 += 32) {
        #pragma unroll
        for (int ch = 0; ch < 2; ch++) {
            int cc = w + ch * 4;
            const u16* ga = A + (size_t)(m0 + cc * 16 + srow) * K + k0 + skc;
            const u16* gb = W + (size_t)(n0 + cc * 16 + srow) * K + k0 + skc;
            __builtin_amdgcn_global_load_lds((AS1 void*)(ga), (AS3 void*)(Alds + cc * 512), 16, 0, 0);
            __builtin_amdgcn_global_load_lds((AS1 void*)(gb), (AS3 void*)(Blds + cc * 512), 16, 0, 0);
        }
        __syncthreads();
        bf16x8 af[4], bfr[4];
        #pragma unroll
        for (int mi = 0; mi < 4; mi++)
            af[mi] = *reinterpret_cast<const bf16x8*>(Alds + (wr * 64 + mi * 16 + c) * 32 + g * 8);
        #pragma unroll
        for (int ni = 0; ni < 4; ni++)
            bfr[ni] = *reinterpret_cast<const bf16x8*>(Blds + (wc * 64 + ni * 16 + c) * 32 + g * 8);
        #pragma unroll
        for (int mi = 0; mi < 4; mi++)
            #pragma unroll
            for (int ni = 0; ni < 4; ni++)
                acc[mi][ni] = __builtin_amdgcn_mfma_f32_16x16x32_bf16(af[mi], bfr[ni], acc[mi][ni], 0, 0, 0);
        __syncthreads();
    }

    if (z < 2) {
        u16* __restrict__ Cout = (z == 0) ? Oq : Ok;
        #pragma unroll
        for (int ni = 0; ni < 4; ni++) {
            int col = n0 + wc * 64 + ni * 16 + c;
            float bv = bias[col];
            #pragma unroll
            for (int mi = 0; mi < 4; mi++)
                #pragma unroll
                for (int i = 0; i < 4; i++) {
                    int row = m0 + wr * 64 + mi * 16 + g * 4 + i;
                    Cout[(size_t)row * N + col] = f2bf(acc[mi][ni][i] + bv);
                }
        }
    } else {
        #pragma unroll
        for (int ni = 0; ni < 4; ni++) {
            int col = n0 + wc * 64 + ni * 16 + c;
            float bv = bias[col];
            int hh = col >> 6, d = col & 63;
            #pragma unroll
            for (int mi = 0; mi < 4; mi++) {
                int row0 = m0 + wr * 64 + mi * 16 + g * 4;
                int bb = row0 >> 11, s = row0 & 2047;
                u32 lo = (u32)f2bf(acc[mi][ni][0] + bv) | ((u32)f2bf(acc[mi][ni][1] + bv) << 16);
                u32 hi = (u32)f2bf(acc[mi][ni][2] + bv) | ((u32)f2bf(acc[mi][ni][3] + bv) << 16);
                size_t idx = ((size_t)((bb * 16 + hh) * 64 + d)) * 2048 + s;
                *reinterpret_cast<uint2*>(Vt + idx) = make_uint2(lo, hi);
            }
        }
    }
}

// ---------------- output GEMM: C = A @ W^T + bias, fp32 out ----------------
__global__ __launch_bounds__(256) void k_gemm_f32(const u16* __restrict__ A, const u16* __restrict__ W,
                                                  const float* __restrict__ bias, float* __restrict__ Cout) {
    __shared__ __attribute__((aligned(16))) u16 Alds[128 * 32];
    __shared__ __attribute__((aligned(16))) u16 Blds[128 * 32];
    const int tid = threadIdx.x;
    const int w = tid >> 6, lane = tid & 63;
    const int wr = w >> 1, wc = w & 1;
    const int c = lane & 15, g = lane >> 4;
    const int m0 = blockIdx.y * 128, n0 = blockIdx.x * 128;
    const int K = 1024, N = 1024;

    floatx4 acc[4][4] = {};
    const int srow = lane >> 2;
    const int skc = (lane & 3) * 8;

    for (int k0 = 0; k0 < K; k0 += 32) {
        #pragma unroll
        for (int ch = 0; ch < 2; ch++) {
            int cc = w + ch * 4;
            const u16* ga = A + (size_t)(m0 + cc * 16 + srow) * K + k0 + skc;
            const u16* gb = W + (size_t)(n0 + cc * 16 + srow) * K + k0 + skc;
            __builtin_amdgcn_global_load_lds((AS1 void*)(ga), (AS3 void*)(Alds + cc * 512), 16, 0, 0);
            __builtin_amdgcn_global_load_lds((AS1 void*)(gb), (AS3 void*)(Blds + cc * 512), 16, 0, 0);
        }
        __syncthreads();
        bf16x8 af[4], bfr[4];
        #pragma unroll
        for (int mi = 0; mi < 4; mi++)
            af[mi] = *reinterpret_cast<const bf16x8*>(Alds + (wr * 64 + mi * 16 + c) * 32 + g * 8);
        #pragma unroll
        for (int ni = 0; ni < 4; ni++)
            bfr[ni] = *reinterpret_cast<const bf16x8*>(Blds + (wc * 64 + ni * 16 + c) * 32 + g * 8);
        #pragma unroll
        for (int mi = 0; mi < 4; mi++)
            #pragma unroll
            for (int ni = 0; ni < 4; ni++)
                acc[mi][ni] = __builtin_amdgcn_mfma_f32_16x16x32_bf16(af[mi], bfr[ni], acc[mi][ni], 0, 0, 0);
        __syncthreads();
    }

    #pragma unroll
    for (int ni = 0; ni < 4; ni++) {
        int col = n0 + wc * 64 + ni * 16 + c;
        float bv = bias[col];
        #pragma unroll
        for (int mi = 0; mi < 4; mi++)
            #pragma unroll
            for (int i = 0; i < 4; i++) {
                int row = m0 + wr * 64 + mi * 16 + g * 4 + i;
                Cout[(size_t)row * N + col] = acc[mi][ni][i] + bv;
            }
    }
}

// ---------------- Flash attention, causal. 4 waves/block, 32 q-rows/wave, KVBLK=64,
// K/V double-buffered in LDS (XOR-swizzled), 2-phase pipeline, defer-max.
// Q,K bf16 [B][S][1024]; Vt bf16 [bh][64][S]; O bf16 [B][S][1024].
__global__ __launch_bounds__(256, 2) void k_attn(const u16* __restrict__ Q, const u16* __restrict__ Kg,
                                                 const u16* __restrict__ Vt, u16* __restrict__ O) {
    __shared__ __attribute__((aligned(16))) u16 Kl[2][64][64];
    __shared__ __attribute__((aligned(16))) u16 Vl[2][64][64];
    __shared__ __attribute__((aligned(16))) __bf16 Pl[4][2][16][88]; // stride 88*2=176B = 11*16B

    const int tid = threadIdx.x;
    const int w = tid >> 6, lane = tid & 63;
    const int c = lane & 15, g = lane >> 4;
    const int lr = lane >> 3, lb = (lane & 7) ^ lr; // staging row-in-chunk / swizzled 16B-block

    // block decode: pair blocks (id, id+256) to constant total work per CU
    const int id = blockIdx.x;
    const int half = id >> 8, r = id & 255;
    int qb = r & 15; if (half) qb = 15 - qb;
    const int bh = (r >> 4) + 16 * half;
    const int b = bh >> 4, h = bh & 15;
    const int q0b = qb * 128;
    const int wq0 = q0b + 32 * w;
    const int rowb = b * 2048, colb = h * 64;
    const u16* __restrict__ Kb = Kg + (size_t)rowb * 1024 + colb;
    const u16* __restrict__ Vb = Vt + (size_t)bh * 64 * 2048;
    const int ntb = 2 * qb + 2;               // block tiles (kv <= q0b+127)
    const int wnt = (wq0 + 31) / 64 + 1;      // this wave's needed tiles

    // Q fragments (32 rows: qi=0,1)
    bf16x8 qf[2][2];
    #pragma unroll
    for (int qi = 0; qi < 2; qi++)
        #pragma unroll
        for (int db = 0; db < 2; db++)
            qf[qi][db] = *reinterpret_cast<const bf16x8*>(
                Q + (size_t)(rowb + wq0 + qi * 16 + c) * 1024 + colb + db * 32 + g * 8);

    // constant "ones" B-fragment for the row-sum column (replaces V ones-row)
    union { u32 u[4]; bf16x8 v; } o8;
    u32 ow = (c == 0) ? 0x3F803F80u : 0u;
    o8.u[0] = ow; o8.u[1] = ow; o8.u[2] = ow; o8.u[3] = ow;

    const float SC = 0.125f * 1.44269504088896f;
    float mx[2][4];
    floatx4 acc[2][5] = {};
    #pragma unroll
    for (int qi = 0; qi < 2; qi++)
        #pragma unroll
        for (int i = 0; i < 4; i++) mx[qi][i] = -1e30f;

    auto STAGE = [&](int bf, int t) {
        const int kv0 = t * 64;
        const u16* gk = Kb + (size_t)(kv0 + 16 * w + lr) * 1024 + lb * 8;
        __builtin_amdgcn_global_load_lds((AS1 void*)gk, (AS3 void*)&Kl[bf][16 * w][0], 16, 0, 0);
        __builtin_amdgcn_global_load_lds((AS1 void*)(gk + 8 * 1024), (AS3 void*)&Kl[bf][16 * w + 8][0], 16, 0, 0);
        const u16* gv = Vb + (size_t)(16 * w + lr) * 2048 + kv0 + lb * 8;
        __builtin_amdgcn_global_load_lds((AS1 void*)gv, (AS3 void*)&Vl[bf][16 * w][0], 16, 0, 0);
        __builtin_amdgcn_global_load_lds((AS1 void*)(gv + 8 * 2048), (AS3 void*)&Vl[bf][16 * w + 8][0], 16, 0, 0);
    };

    STAGE(0, 0);
    __syncthreads();

    for (int t = 0; t < ntb; t++) {
        const int bf = t & 1;
        const int kv0 = t * 64;
        if (t + 1 < ntb) STAGE(bf ^ 1, t + 1);

        if (t < wnt) {
            // K fragments from LDS (swizzled) + QK^T
            bf16x8 kf[4][2];
            #pragma unroll
            for (int cb = 0; cb < 4; cb++)
                #pragma unroll
                for (int db = 0; db < 2; db++)
                    kf[cb][db] = *reinterpret_cast<const bf16x8*>(
                        &Kl[bf][cb * 16 + c][((((db << 2) | g) ^ (c & 7)) << 3)]);
            floatx4 s4[2][4] = {};
            #pragma unroll
            for (int qi = 0; qi < 2; qi++)
                #pragma unroll
                for (int cb = 0; cb < 4; cb++)
                    #pragma unroll
                    for (int db = 0; db < 2; db++)
                        s4[qi][cb] = __builtin_amdgcn_mfma_f32_16x16x32_bf16(qf[qi][db], kf[cb][db], s4[qi][cb], 0, 0, 0);

            // V fragments (issue early; consumed after softmax)
            bf16x8 vf[4][2];
            #pragma unroll
            for (int vb = 0; vb < 4; vb++)
                #pragma unroll
                for (int ks = 0; ks < 2; ks++)
                    vf[vb][ks] = *reinterpret_cast<const bf16x8*>(
                        &Vl[bf][vb * 16 + c][((((ks << 2) | g) ^ (c & 7)) << 3)]);

            const bool diag = (kv0 + 63 > wq0);
            #pragma unroll
            for (int qi = 0; qi < 2; qi++) {
                float p[4][4];
                #pragma unroll
                for (int cb = 0; cb < 4; cb++)
                    #pragma unroll
                    for (int i = 0; i < 4; i++) {
                        float sv = s4[qi][cb][i] * SC;
                        if (diag && (kv0 + cb * 16 + c > wq0 + qi * 16 + g * 4 + i)) sv = -1e30f;
                        p[cb][i] = sv;
                    }
                float rm[4];
                bool grow = false;
                #pragma unroll
                for (int i = 0; i < 4; i++) {
                    float v = fmaxf(fmaxf(p[0][i], p[1][i]), fmaxf(p[2][i], p[3][i]));
                    #pragma unroll
                    for (int off = 1; off < 16; off <<= 1)
                        v = fmaxf(v, __shfl_xor(v, off));
                    rm[i] = v;
                    grow = grow || (v > mx[qi][i] + 8.f);
                }
                if (__any(grow)) {
                    #pragma unroll
                    for (int i = 0; i < 4; i++) {
                        float mn = fmaxf(mx[qi][i], rm[i]);
                        float corr = exp2f(mx[qi][i] - mn);
                        mx[qi][i] = mn;
                        #pragma unroll
                        for (int vb = 0; vb < 5; vb++)
                            acc[qi][vb][i] *= corr;
                    }
                }
                #pragma unroll
                for (int cb = 0; cb < 4; cb++)
                    #pragma unroll
                    for (int i = 0; i < 4; i++)
                        Pl[w][qi][g * 4 + i][cb * 16 + c] = (__bf16)exp2f(p[cb][i] - mx[qi][i]);
            }
            // P fragments + PV
            bf16x8 pf[2][2];
            #pragma unroll
            for (int qi = 0; qi < 2; qi++)
                #pragma unroll
                for (int ks = 0; ks < 2; ks++)
                    pf[qi][ks] = *reinterpret_cast<const bf16x8*>(&Pl[w][qi][c][ks * 32 + g * 8]);
            #pragma unroll
            for (int qi = 0; qi < 2; qi++)
                #pragma unroll
                for (int ks = 0; ks < 2; ks++) {
                    #pragma unroll
                    for (int vb = 0; vb < 4; vb++)
                        acc[qi][vb] = __builtin_amdgcn_mfma_f32_16x16x32_bf16(pf[qi][ks], vf[vb][ks], acc[qi][vb], 0, 0, 0);
                    acc[qi][4] = __builtin_amdgcn_mfma_f32_16x16x32_bf16(pf[qi][ks], o8.v, acc[qi][4], 0, 0, 0);
                }
        }
        __syncthreads();
    }

    #pragma unroll
    for (int qi = 0; qi < 2; qi++)
        #pragma unroll
        for (int i = 0; i < 4; i++) {
            float ls = __shfl(acc[qi][4][i], g << 4); // sum column (c==0 lane of own group)
            float inv = 1.f / ls;
            #pragma unroll
            for (int vb = 0; vb < 4; vb++)
                O[(size_t)(rowb + wq0 + qi * 16 + g * 4 + i) * 1024 + colb + vb * 16 + c] =
                    f2bf(acc[qi][vb][i] * inv);
        }
}

extern "C" void kernel_launch(void* const* d_in, const int* in_sizes, int n_in,
                              void* d_out, int out_size, void* d_ws, size_t ws_size,
                              hipStream_t stream) {
    const float* x  = (const float*)d_in[0];
    const float* wq = (const float*)d_in[1];
    const float* bq = (const float*)d_in[2];
    const float* wk = (const float*)d_in[3];
    const float* bk = (const float*)d_in[4];
    const float* wv = (const float*)d_in[5];
    const float* bv = (const float*)d_in[6];
    const float* wo = (const float*)d_in[7];
    const float* bo = (const float*)d_in[8];

    char* ws = (char*)d_ws;
    u16* xb  = (u16*)(ws);                      // 8 MiB [4096][1024]
    u16* wqb = (u16*)(ws + (8ull  << 20));      // 2 MiB each
    u16* wkb = (u16*)(ws + (10ull << 20));
    u16* wvb = (u16*)(ws + (12ull << 20));
    u16* wob = (u16*)(ws + (14ull << 20));
    u16* qg  = (u16*)(ws + (16ull << 20));      // 8 MiB
    u16* kg  = (u16*)(ws + (24ull << 20));      // 8 MiB
    u16* vt  = (u16*)(ws + (32ull << 20));      // 8 MiB [32][64][2048]
    u16* og  = (u16*)(ws + (40ull << 20));      // 8 MiB
    float* ct = (float*)(ws + (48ull << 20));   // 512 KiB
    float* st = (float*)(ws + (49ull << 20));   // 512 KiB

    k_f2b<<<4096, 256, 0, stream>>>(x,  xb,  1048576);
    k_f2b<<<1024, 256, 0, stream>>>(wq, wqb, 262144);
    k_f2b<<<1024, 256, 0, stream>>>(wk, wkb, 262144);
    k_f2b<<<1024, 256, 0, stream>>>(wv, wvb, 262144);
    k_f2b<<<1024, 256, 0, stream>>>(wo, wob, 262144);
    k_rope_tab<<<512, 256, 0, stream>>>(ct, st);

    dim3 gq(8, 32, 3);
    k_gemm_qkv<<<gq, 256, 0, stream>>>(xb, wqb, wkb, wvb, bq, bk, bv, qg, kg, vt);

    k_rope_apply<<<8192, 256, 0, stream>>>(qg, kg, ct, st);

    k_attn<<<512, 256, 0, stream>>>(qg, kg, vt, og);

    k_gemm_f32<<<dim3(8, 32), 256, 0, stream>>>(og, wob, bo, (float*)d_out);
}

// Round 4
// 174.748 us; speedup vs baseline: 2.0515x; 1.1172x over previous
//
#include <hip/hip_runtime.h>

typedef unsigned short u16;
typedef unsigned int u32;
typedef __bf16 bf16x8 __attribute__((ext_vector_type(8)));
typedef float floatx4 __attribute__((ext_vector_type(4)));
typedef float floatx16 __attribute__((ext_vector_type(16)));

#define AS1 __attribute__((address_space(1)))
#define AS3 __attribute__((address_space(3)))

__device__ __forceinline__ u16 f2bf(float f) {
    union { float f; u32 u; } a; a.f = f;
    u32 u = a.u;
    u32 r = (u + 0x7fffu + ((u >> 16) & 1u)) >> 16;
    return (u16)r;
}
__device__ __forceinline__ float bf2f(u16 h) {
    union { u32 u; float f; } a; a.u = ((u32)h) << 16; return a.f;
}
__device__ __forceinline__ u32 cvtpk(float a, float b) {
    u32 d; asm("v_cvt_pk_bf16_f32 %0, %1, %2" : "=v"(d) : "v"(a), "v"(b)); return d;
}
__device__ __forceinline__ void plswap(u32& a, u32& b) {
    asm("v_permlane32_swap_b32 %0, %1" : "+v"(a), "+v"(b));
}

// ---------------- fp32 -> bf16 cast ----------------
__global__ void k_f2b(const float* __restrict__ in, u16* __restrict__ out, int n4) {
    int i = blockIdx.x * blockDim.x + threadIdx.x;
    if (i >= n4) return;
    float4 v = reinterpret_cast<const float4*>(in)[i];
    u32 lo = (u32)f2bf(v.x) | ((u32)f2bf(v.y) << 16);
    u32 hi = (u32)f2bf(v.z) | ((u32)f2bf(v.w) << 16);
    reinterpret_cast<uint2*>(out)[i] = make_uint2(lo, hi);
}

// ---------------- RoPE tables ----------------
__global__ void k_rope_tab(float* __restrict__ ct, float* __restrict__ st) {
    int i = blockIdx.x * blockDim.x + threadIdx.x; // 2048*64
    if (i >= 2048 * 64) return;
    int s = i >> 6, d = i & 63;
    float inv = powf(10000.f, -(float)(d & 31) * (1.f / 32.f));
    float ang = (float)s * inv;
    ct[i] = cosf(ang);
    st[i] = sinf(ang);
}

// ---------------- RoPE in-place on q,k ----------------
__global__ void k_rope_apply(u16* __restrict__ q, u16* __restrict__ k,
                             const float* __restrict__ ct, const float* __restrict__ st) {
    int t = blockIdx.x * blockDim.x + threadIdx.x;
    int d2 = t & 31; int h = (t >> 5) & 15; int s = (t >> 9) & 2047; int b = t >> 20;
    int d0 = d2 * 2;
    int base = ((b * 2048 + s) * 1024) + h * 64 + d0;
    int tb = s * 64 + d0;
    float c0 = ct[tb], c1 = ct[tb + 1], s0 = st[tb], s1 = st[tb + 1];
    u32 qv = *reinterpret_cast<u32*>(q + base);
    float q0 = bf2f((u16)qv), q1 = bf2f((u16)(qv >> 16));
    float r0 = q0 * c0 - q1 * s0;
    float r1 = q1 * c1 + q0 * s1;
    *reinterpret_cast<u32*>(q + base) = (u32)f2bf(r0) | ((u32)f2bf(r1) << 16);
    u32 kv = *reinterpret_cast<u32*>(k + base);
    float k0 = bf2f((u16)kv), k1 = bf2f((u16)(kv >> 16));
    float t0 = k0 * c0 - k1 * s0;
    float t1 = k1 * c1 + k0 * s1;
    *reinterpret_cast<u32*>(k + base) = (u32)f2bf(t0) | ((u32)f2bf(t1) << 16);
}

// ---------------- fused QKV GEMM: z=0->Q, z=1->K rowmajor; z=2->V transposed [bh][64][S] ----
__global__ __launch_bounds__(256) void k_gemm_qkv(const u16* __restrict__ A,
        const u16* __restrict__ Wq, const u16* __restrict__ Wk, const u16* __restrict__ Wv,
        const float* __restrict__ Bq, const float* __restrict__ Bk, const float* __restrict__ Bv,
        u16* __restrict__ Oq, u16* __restrict__ Ok, u16* __restrict__ Vt) {
    __shared__ __attribute__((aligned(16))) u16 Alds[128 * 32];
    __shared__ __attribute__((aligned(16))) u16 Blds[128 * 32];
    const int z = blockIdx.z;
    const u16* __restrict__ W = (z == 0) ? Wq : (z == 1) ? Wk : Wv;
    const float* __restrict__ bias = (z == 0) ? Bq : (z == 1) ? Bk : Bv;
    const int tid = threadIdx.x;
    const int w = tid >> 6, lane = tid & 63;
    const int wr = w >> 1, wc = w & 1;
    const int c = lane & 15, g = lane >> 4;
    const int m0 = blockIdx.y * 128, n0 = blockIdx.x * 128;
    const int K = 1024, N = 1024;

    floatx4 acc[4][4] = {};
    const int srow = lane >> 2;
    const int skc = (lane & 3) * 8;

    for (int k0 = 0; k0 < K; k0 += 32) {
        #pragma unroll
        for (int ch = 0; ch < 2; ch++) {
            int cc = w + ch * 4;
            const u16* ga = A + (size_t)(m0 + cc * 16 + srow) * K + k0 + skc;
            const u16* gb = W + (size_t)(n0 + cc * 16 + srow) * K + k0 + skc;
            __builtin_amdgcn_global_load_lds((AS1 void*)(ga), (AS3 void*)(Alds + cc * 512), 16, 0, 0);
            __builtin_amdgcn_global_load_lds((AS1 void*)(gb), (AS3 void*)(Blds + cc * 512), 16, 0, 0);
        }
        __syncthreads();
        bf16x8 af[4], bfr[4];
        #pragma unroll
        for (int mi = 0; mi < 4; mi++)
            af[mi] = *reinterpret_cast<const bf16x8*>(Alds + (wr * 64 + mi * 16 + c) * 32 + g * 8);
        #pragma unroll
        for (int ni = 0; ni < 4; ni++)
            bfr[ni] = *reinterpret_cast<const bf16x8*>(Blds + (wc * 64 + ni * 16 + c) * 32 + g * 8);
        #pragma unroll
        for (int mi = 0; mi < 4; mi++)
            #pragma unroll
            for (int ni = 0; ni < 4; ni++)
                acc[mi][ni] = __builtin_amdgcn_mfma_f32_16x16x32_bf16(af[mi], bfr[ni], acc[mi][ni], 0, 0, 0);
        __syncthreads();
    }

    if (z < 2) {
        u16* __restrict__ Cout = (z == 0) ? Oq : Ok;
        #pragma unroll
        for (int ni = 0; ni < 4; ni++) {
            int col = n0 + wc * 64 + ni * 16 + c;
            float bv = bias[col];
            #pragma unroll
            for (int mi = 0; mi < 4; mi++)
                #pragma unroll
                for (int i = 0; i < 4; i++) {
                    int row = m0 + wr * 64 + mi * 16 + g * 4 + i;
                    Cout[(size_t)row * N + col] = f2bf(acc[mi][ni][i] + bv);
                }
        }
    } else {
        #pragma unroll
        for (int ni = 0; ni < 4; ni++) {
            int col = n0 + wc * 64 + ni * 16 + c;
            float bv = bias[col];
            int hh = col >> 6, d = col & 63;
            #pragma unroll
            for (int mi = 0; mi < 4; mi++) {
                int row0 = m0 + wr * 64 + mi * 16 + g * 4;
                int bb = row0 >> 11, s = row0 & 2047;
                u32 lo = (u32)f2bf(acc[mi][ni][0] + bv) | ((u32)f2bf(acc[mi][ni][1] + bv) << 16);
                u32 hi = (u32)f2bf(acc[mi][ni][2] + bv) | ((u32)f2bf(acc[mi][ni][3] + bv) << 16);
                size_t idx = ((size_t)((bb * 16 + hh) * 64 + d)) * 2048 + s;
                *reinterpret_cast<uint2*>(Vt + idx) = make_uint2(lo, hi);
            }
        }
    }
}

// ---------------- output GEMM: C = A @ W^T + bias, fp32 out ----------------
__global__ __launch_bounds__(256) void k_gemm_f32(const u16* __restrict__ A, const u16* __restrict__ W,
                                                  const float* __restrict__ bias, float* __restrict__ Cout) {
    __shared__ __attribute__((aligned(16))) u16 Alds[128 * 32];
    __shared__ __attribute__((aligned(16))) u16 Blds[128 * 32];
    const int tid = threadIdx.x;
    const int w = tid >> 6, lane = tid & 63;
    const int wr = w >> 1, wc = w & 1;
    const int c = lane & 15, g = lane >> 4;
    const int m0 = blockIdx.y * 128, n0 = blockIdx.x * 128;
    const int K = 1024, N = 1024;

    floatx4 acc[4][4] = {};
    const int srow = lane >> 2;
    const int skc = (lane & 3) * 8;

    for (int k0 = 0; k0 < K; k0 += 32) {
        #pragma unroll
        for (int ch = 0; ch < 2; ch++) {
            int cc = w + ch * 4;
            const u16* ga = A + (size_t)(m0 + cc * 16 + srow) * K + k0 + skc;
            const u16* gb = W + (size_t)(n0 + cc * 16 + srow) * K + k0 + skc;
            __builtin_amdgcn_global_load_lds((AS1 void*)(ga), (AS3 void*)(Alds + cc * 512), 16, 0, 0);
            __builtin_amdgcn_global_load_lds((AS1 void*)(gb), (AS3 void*)(Blds + cc * 512), 16, 0, 0);
        }
        __syncthreads();
        bf16x8 af[4], bfr[4];
        #pragma unroll
        for (int mi = 0; mi < 4; mi++)
            af[mi] = *reinterpret_cast<const bf16x8*>(Alds + (wr * 64 + mi * 16 + c) * 32 + g * 8);
        #pragma unroll
        for (int ni = 0; ni < 4; ni++)
            bfr[ni] = *reinterpret_cast<const bf16x8*>(Blds + (wc * 64 + ni * 16 + c) * 32 + g * 8);
        #pragma unroll
        for (int mi = 0; mi < 4; mi++)
            #pragma unroll
            for (int ni = 0; ni < 4; ni++)
                acc[mi][ni] = __builtin_amdgcn_mfma_f32_16x16x32_bf16(af[mi], bfr[ni], acc[mi][ni], 0, 0, 0);
        __syncthreads();
    }

    #pragma unroll
    for (int ni = 0; ni < 4; ni++) {
        int col = n0 + wc * 64 + ni * 16 + c;
        float bv = bias[col];
        #pragma unroll
        for (int mi = 0; mi < 4; mi++)
            #pragma unroll
            for (int i = 0; i < 4; i++) {
                int row = m0 + wr * 64 + mi * 16 + g * 4 + i;
                Cout[(size_t)row * N + col] = acc[mi][ni][i] + bv;
            }
    }
}

// ---------------- Flash attention, causal, swapped-operand 32x32x16 structure.
// Each lane owns one q-column of S^T (col=lane&31); softmax in-register; P^T B-frags
// via cvt_pk + permlane32_swap; O^T accumulated (col=q -> lane-local rescale).
// Q,K bf16 [B][S][1024]; Vt bf16 [bh][64][S]; O bf16 [B][S][1024].
__global__ __launch_bounds__(256, 2) void k_attn(const u16* __restrict__ Q, const u16* __restrict__ Kg,
                                                 const u16* __restrict__ Vt, u16* __restrict__ O) {
    __shared__ __attribute__((aligned(16))) u16 Kl[2][64][64]; // [kv][d], 16B-blocks swizzled by row&7
    __shared__ __attribute__((aligned(16))) u16 Vl[2][64][64]; // [d][s], swizzled likewise

    const int tid = threadIdx.x;
    const int w = tid >> 6, lane = tid & 63;
    const int l31 = lane & 31, hi = lane >> 5;
    const int lr = lane >> 3, lb = (lane & 7) ^ (lr & 7);
    const int sw = l31 & 7; // read-side swizzle key (row&7 for all our LDS rows)

    // block decode: pair blocks (id, id+256) so per-CU work is constant
    const int id = blockIdx.x;
    const int half = id >> 8, r = id & 255;
    int qb = r & 15; if (half) qb = 15 - qb;
    const int bh = (r >> 4) + 16 * half;
    const int b = bh >> 4, h = bh & 15;
    const int q0b = qb * 128;
    const int wq0 = q0b + 32 * w;
    const int rowb = b * 2048, colb = h * 64;
    const u16* __restrict__ Kb = Kg + (size_t)rowb * 1024 + colb;
    const u16* __restrict__ Vb = Vt + (size_t)bh * 64 * 2048;
    const int ntb = 2 * qb + 2;
    const int wnt = (wq0 + 31) / 64 + 1;
    const int myq = wq0 + l31;

    // Q B-frags (4 d-steps of 16): qf[s][j] = Q[myq][s*16 + hi*8 + j]
    bf16x8 qf[4];
    #pragma unroll
    for (int s = 0; s < 4; s++)
        qf[s] = *reinterpret_cast<const bf16x8*>(Q + (size_t)(rowb + myq) * 1024 + colb + s * 16 + hi * 8);

    const float SC = 0.125f * 1.44269504088896f;
    float mreg = -1e30f, ls = 0.f;
    floatx16 acc0 = {}, acc1 = {}; // O^T: d rows 0..31 / 32..63, col = myq

    auto STAGE = [&](int bf, int t) {
        const int kv0s = t * 64;
        const u16* gk = Kb + (size_t)(kv0s + 16 * w + lr) * 1024 + lb * 8;
        __builtin_amdgcn_global_load_lds((AS1 void*)gk, (AS3 void*)&Kl[bf][16 * w][0], 16, 0, 0);
        __builtin_amdgcn_global_load_lds((AS1 void*)(gk + 8 * 1024), (AS3 void*)&Kl[bf][16 * w + 8][0], 16, 0, 0);
        const u16* gv = Vb + (size_t)(16 * w + lr) * 2048 + kv0s + lb * 8;
        __builtin_amdgcn_global_load_lds((AS1 void*)gv, (AS3 void*)&Vl[bf][16 * w][0], 16, 0, 0);
        __builtin_amdgcn_global_load_lds((AS1 void*)(gv + 8 * 2048), (AS3 void*)&Vl[bf][16 * w + 8][0], 16, 0, 0);
    };

    STAGE(0, 0);
    __syncthreads();

    for (int t = 0; t < ntb; t++) {
        const int bf = t & 1;
        const int kv0 = t * 64;
        if (t + 1 < ntb) STAGE(bf ^ 1, t + 1);

        if (t < wnt) {
            #pragma unroll
            for (int kb = 0; kb < 2; kb++) {
                const int kvb = kv0 + kb * 32;
                if (kvb <= wq0 + 31) { // wave-uniform
                    // S^T = K @ Q^T : 4 mfma over d
                    floatx16 st4 = {};
                    __builtin_amdgcn_s_setprio(1);
                    #pragma unroll
                    for (int s = 0; s < 4; s++) {
                        bf16x8 kf = *reinterpret_cast<const bf16x8*>(
                            &Kl[bf][kb * 32 + l31][(((s * 2 + hi) ^ sw) << 3)]);
                        st4 = __builtin_amdgcn_mfma_f32_32x32x16_bf16(kf, qf[s], st4, 0, 0, 0);
                    }
                    __builtin_amdgcn_s_setprio(0);

                    // scale + causal mask; p[rr] = S[myq][kvb + (rr&3)+8*(rr>>2)+4*hi]
                    float p[16];
                    const bool diag = (kvb + 31 > wq0); // wave-uniform
                    #pragma unroll
                    for (int rr = 0; rr < 16; rr++) {
                        float sv = st4[rr] * SC;
                        if (diag) {
                            int kv = kvb + (rr & 3) + 8 * (rr >> 2) + 4 * hi;
                            if (kv > myq) sv = -1e30f;
                        }
                        p[rr] = sv;
                    }
                    // row max (in-register tree + lane^32 exchange)
                    float pm = fmaxf(
                        fmaxf(fmaxf(fmaxf(p[0], p[1]), fmaxf(p[2], p[3])),
                              fmaxf(fmaxf(p[4], p[5]), fmaxf(p[6], p[7]))),
                        fmaxf(fmaxf(fmaxf(p[8], p[9]), fmaxf(p[10], p[11])),
                              fmaxf(fmaxf(p[12], p[13]), fmaxf(p[14], p[15]))));
                    pm = fmaxf(pm, __shfl_xor(pm, 32));
                    if (__any(pm > mreg + 8.f)) { // defer-max (THR=8)
                        float mn = fmaxf(mreg, pm);
                        float corr = exp2f(mreg - mn);
                        mreg = mn;
                        ls *= corr;
                        acc0 *= corr;
                        acc1 *= corr;
                    }
                    // exp + row sum
                    #pragma unroll
                    for (int rr = 0; rr < 16; rr++) p[rr] = exp2f(p[rr] - mreg);
                    float sm = ((p[0] + p[1]) + (p[2] + p[3])) + ((p[4] + p[5]) + (p[6] + p[7]))
                             + ((p[8] + p[9]) + (p[10] + p[11])) + ((p[12] + p[13]) + (p[14] + p[15]));
                    sm += __shfl_xor(sm, 32);
                    ls += sm;

                    // P^T B-frags: step0 from p[0..7], step1 from p[8..15]
                    union { u32 u[4]; bf16x8 v; } f0, f1;
                    {
                        u32 a0 = cvtpk(p[0], p[1]), b0 = cvtpk(p[4], p[5]);
                        u32 c0 = cvtpk(p[2], p[3]), d0 = cvtpk(p[6], p[7]);
                        plswap(a0, b0); plswap(c0, d0);
                        f0.u[0] = a0; f0.u[1] = c0; f0.u[2] = b0; f0.u[3] = d0;
                        u32 e1 = cvtpk(p[8], p[9]),  g1 = cvtpk(p[12], p[13]);
                        u32 h1 = cvtpk(p[10], p[11]), i1 = cvtpk(p[14], p[15]);
                        plswap(e1, g1); plswap(h1, i1);
                        f1.u[0] = e1; f1.u[1] = h1; f1.u[2] = g1; f1.u[3] = i1;
                    }
                    // O^T += V^T @ P^T : 2 k-steps x 2 d-tiles
                    __builtin_amdgcn_s_setprio(1);
                    #pragma unroll
                    for (int s = 0; s < 2; s++) {
                        const int blk = (kb * 4 + s * 2 + hi) ^ sw;
                        bf16x8 v0 = *reinterpret_cast<const bf16x8*>(&Kl[0][0][0] + 0); // placeholder avoided below
                        v0 = *reinterpret_cast<const bf16x8*>(&Vl[bf][l31][blk << 3]);
                        bf16x8 v1 = *reinterpret_cast<const bf16x8*>(&Vl[bf][32 + l31][blk << 3]);
                        const bf16x8 pf = (s == 0) ? f0.v : f1.v;
                        acc0 = __builtin_amdgcn_mfma_f32_32x32x16_bf16(v0, pf, acc0, 0, 0, 0);
                        acc1 = __builtin_amdgcn_mfma_f32_32x32x16_bf16(v1, pf, acc1, 0, 0, 0);
                    }
                    __builtin_amdgcn_s_setprio(0);
                }
            }
        }
        __syncthreads();
    }

    // epilogue: O[rowb+myq][colb + d], d = 32*db + 8*g + 4*hi + (0..3)
    const float inv = 1.f / ls;
    u16* __restrict__ Orow = O + (size_t)(rowb + myq) * 1024 + colb;
    #pragma unroll
    for (int db = 0; db < 2; db++) {
        const floatx16& a = db ? acc1 : acc0;
        #pragma unroll
        for (int g4 = 0; g4 < 4; g4++) {
            u32 lo = cvtpk(a[g4 * 4 + 0] * inv, a[g4 * 4 + 1] * inv);
            u32 hh = cvtpk(a[g4 * 4 + 2] * inv, a[g4 * 4 + 3] * inv);
            *reinterpret_cast<uint2*>(Orow + db * 32 + g4 * 8 + hi * 4) = make_uint2(lo, hh);
        }
    }
}

extern "C" void kernel_launch(void* const* d_in, const int* in_sizes, int n_in,
                              void* d_out, int out_size, void* d_ws, size_t ws_size,
                              hipStream_t stream) {
    const float* x  = (const float*)d_in[0];
    const float* wq = (const float*)d_in[1];
    const float* bq = (const float*)d_in[2];
    const float* wk = (const float*)d_in[3];
    const float* bk = (const float*)d_in[4];
    const float* wv = (const float*)d_in[5];
    const float* bv = (const float*)d_in[6];
    const float* wo = (const float*)d_in[7];
    const float* bo = (const float*)d_in[8];

    char* ws = (char*)d_ws;
    u16* xb  = (u16*)(ws);                      // 8 MiB [4096][1024]
    u16* wqb = (u16*)(ws + (8ull  << 20));      // 2 MiB each
    u16* wkb = (u16*)(ws + (10ull << 20));
    u16* wvb = (u16*)(ws + (12ull << 20));
    u16* wob = (u16*)(ws + (14ull << 20));
    u16* qg  = (u16*)(ws + (16ull << 20));      // 8 MiB
    u16* kg  = (u16*)(ws + (24ull << 20));      // 8 MiB
    u16* vt  = (u16*)(ws + (32ull << 20));      // 8 MiB [32][64][2048]
    u16* og  = (u16*)(ws + (40ull << 20));      // 8 MiB
    float* ct = (float*)(ws + (48ull << 20));   // 512 KiB
    float* st = (float*)(ws + (49ull << 20));   // 512 KiB

    k_f2b<<<4096, 256, 0, stream>>>(x,  xb,  1048576);
    k_f2b<<<1024, 256, 0, stream>>>(wq, wqb, 262144);
    k_f2b<<<1024, 256, 0, stream>>>(wk, wkb, 262144);
    k_f2b<<<1024, 256, 0, stream>>>(wv, wvb, 262144);
    k_f2b<<<1024, 256, 0, stream>>>(wo, wob, 262144);
    k_rope_tab<<<512, 256, 0, stream>>>(ct, st);

    dim3 gq(8, 32, 3);
    k_gemm_qkv<<<gq, 256, 0, stream>>>(xb, wqb, wkb, wvb, bq, bk, bv, qg, kg, vt);

    k_rope_apply<<<8192, 256, 0, stream>>>(qg, kg, ct, st);

    k_attn<<<512, 256, 0, stream>>>(qg, kg, vt, og);

    k_gemm_f32<<<dim3(8, 32), 256, 0, stream>>>(og, wob, bo, (float*)d_out);
}

// Round 6
// 167.282 us; speedup vs baseline: 2.1430x; 1.0446x over previous
//
#include <hip/hip_runtime.h>

typedef unsigned short u16;
typedef unsigned int u32;
typedef __bf16 bf16x8 __attribute__((ext_vector_type(8)));
typedef float floatx4 __attribute__((ext_vector_type(4)));
typedef float floatx16 __attribute__((ext_vector_type(16)));

#define AS1 __attribute__((address_space(1)))
#define AS3 __attribute__((address_space(3)))

__device__ __forceinline__ u16 f2bf(float f) {
    union { float f; u32 u; } a; a.f = f;
    u32 u = a.u;
    u32 r = (u + 0x7fffu + ((u >> 16) & 1u)) >> 16;
    return (u16)r;
}
__device__ __forceinline__ float bf2f(u16 h) {
    union { u32 u; float f; } a; a.u = ((u32)h) << 16; return a.f;
}
__device__ __forceinline__ u32 cvtpk(float a, float b) {
    u32 d; asm("v_cvt_pk_bf16_f32 %0, %1, %2" : "=v"(d) : "v"(a), "v"(b)); return d;
}
__device__ __forceinline__ void plswap(u32& a, u32& b) {
    asm("v_permlane32_swap_b32 %0, %1" : "+v"(a), "+v"(b));
}

// ---------------- consolidated prep: casts (x, wq, wk, wv, wo) + RoPE tables ----------------
// x: 1048576 quads; weights: 4 x 262144 quads; tables: 131072 elements. total 2228224 threads.
__global__ void k_prep(const float* __restrict__ x,
                       const float* __restrict__ wq, const float* __restrict__ wk,
                       const float* __restrict__ wv, const float* __restrict__ wo,
                       u16* __restrict__ xb, u16* __restrict__ wqb, u16* __restrict__ wkb,
                       u16* __restrict__ wvb, u16* __restrict__ wob,
                       float* __restrict__ ct, float* __restrict__ st) {
    int g = blockIdx.x * blockDim.x + threadIdx.x;
    if (g < 2097152) {
        const float* src; u16* dst; int q;
        if (g < 1048576) { src = x; dst = xb; q = g; }
        else {
            int r = g - 1048576, wsel = r >> 18; q = r & 262143;
            src = (wsel == 0) ? wq : (wsel == 1) ? wk : (wsel == 2) ? wv : wo;
            dst = (wsel == 0) ? wqb : (wsel == 1) ? wkb : (wsel == 2) ? wvb : wob;
        }
        float4 v = reinterpret_cast<const float4*>(src)[q];
        u32 lo = (u32)f2bf(v.x) | ((u32)f2bf(v.y) << 16);
        u32 hi = (u32)f2bf(v.z) | ((u32)f2bf(v.w) << 16);
        reinterpret_cast<uint2*>(dst)[q] = make_uint2(lo, hi);
    } else if (g < 2228224) {
        int i = g - 2097152; // 2048*64
        int s = i >> 6, d = i & 63;
        float inv = powf(10000.f, -(float)(d & 31) * (1.f / 32.f));
        float ang = (float)s * inv;
        ct[i] = cosf(ang);
        st[i] = sinf(ang);
    }
}

// ---------------- RoPE in-place on q,k; q additionally pre-scaled by 0.125*log2(e) ----------------
__global__ void k_rope_apply(u16* __restrict__ q, u16* __restrict__ k,
                             const float* __restrict__ ct, const float* __restrict__ st) {
    const float SC = 0.125f * 1.44269504088896f;
    int t = blockIdx.x * blockDim.x + threadIdx.x;
    int d2 = t & 31; int h = (t >> 5) & 15; int s = (t >> 9) & 2047; int b = t >> 20;
    int d0 = d2 * 2;
    int base = ((b * 2048 + s) * 1024) + h * 64 + d0;
    int tb = s * 64 + d0;
    float c0 = ct[tb], c1 = ct[tb + 1], s0 = st[tb], s1 = st[tb + 1];
    u32 qv = *reinterpret_cast<u32*>(q + base);
    float q0 = bf2f((u16)qv), q1 = bf2f((u16)(qv >> 16));
    float r0 = (q0 * c0 - q1 * s0) * SC;
    float r1 = (q1 * c1 + q0 * s1) * SC;
    *reinterpret_cast<u32*>(q + base) = (u32)f2bf(r0) | ((u32)f2bf(r1) << 16);
    u32 kv = *reinterpret_cast<u32*>(k + base);
    float k0 = bf2f((u16)kv), k1 = bf2f((u16)(kv >> 16));
    float t0 = k0 * c0 - k1 * s0;
    float t1 = k1 * c1 + k0 * s1;
    *reinterpret_cast<u32*>(k + base) = (u32)f2bf(t0) | ((u32)f2bf(t1) << 16);
}

// ---------------- fused QKV GEMM: z=0->Q, z=1->K rowmajor; z=2->V transposed [bh][64][S] ----
__global__ __launch_bounds__(256) void k_gemm_qkv(const u16* __restrict__ A,
        const u16* __restrict__ Wq, const u16* __restrict__ Wk, const u16* __restrict__ Wv,
        const float* __restrict__ Bq, const float* __restrict__ Bk, const float* __restrict__ Bv,
        u16* __restrict__ Oq, u16* __restrict__ Ok, u16* __restrict__ Vt) {
    __shared__ __attribute__((aligned(16))) u16 Alds[128 * 32];
    __shared__ __attribute__((aligned(16))) u16 Blds[128 * 32];
    const int z = blockIdx.z;
    const u16* __restrict__ W = (z == 0) ? Wq : (z == 1) ? Wk : Wv;
    const float* __restrict__ bias = (z == 0) ? Bq : (z == 1) ? Bk : Bv;
    const int tid = threadIdx.x;
    const int w = tid >> 6, lane = tid & 63;
    const int wr = w >> 1, wc = w & 1;
    const int c = lane & 15, g = lane >> 4;
    const int m0 = blockIdx.y * 128, n0 = blockIdx.x * 128;
    const int K = 1024, N = 1024;

    floatx4 acc[4][4] = {};
    const int srow = lane >> 2;
    const int skc = (lane & 3) * 8;

    for (int k0 = 0; k0 < K; k0 += 32) {
        #pragma unroll
        for (int ch = 0; ch < 2; ch++) {
            int cc = w + ch * 4;
            const u16* ga = A + (size_t)(m0 + cc * 16 + srow) * K + k0 + skc;
            const u16* gb = W + (size_t)(n0 + cc * 16 + srow) * K + k0 + skc;
            __builtin_amdgcn_global_load_lds((AS1 void*)(ga), (AS3 void*)(Alds + cc * 512), 16, 0, 0);
            __builtin_amdgcn_global_load_lds((AS1 void*)(gb), (AS3 void*)(Blds + cc * 512), 16, 0, 0);
        }
        __syncthreads();
        bf16x8 af[4], bfr[4];
        #pragma unroll
        for (int mi = 0; mi < 4; mi++)
            af[mi] = *reinterpret_cast<const bf16x8*>(Alds + (wr * 64 + mi * 16 + c) * 32 + g * 8);
        #pragma unroll
        for (int ni = 0; ni < 4; ni++)
            bfr[ni] = *reinterpret_cast<const bf16x8*>(Blds + (wc * 64 + ni * 16 + c) * 32 + g * 8);
        #pragma unroll
        for (int mi = 0; mi < 4; mi++)
            #pragma unroll
            for (int ni = 0; ni < 4; ni++)
                acc[mi][ni] = __builtin_amdgcn_mfma_f32_16x16x32_bf16(af[mi], bfr[ni], acc[mi][ni], 0, 0, 0);
        __syncthreads();
    }

    if (z < 2) {
        u16* __restrict__ Cout = (z == 0) ? Oq : Ok;
        #pragma unroll
        for (int ni = 0; ni < 4; ni++) {
            int col = n0 + wc * 64 + ni * 16 + c;
            float bv = bias[col];
            #pragma unroll
            for (int mi = 0; mi < 4; mi++)
                #pragma unroll
                for (int i = 0; i < 4; i++) {
                    int row = m0 + wr * 64 + mi * 16 + g * 4 + i;
                    Cout[(size_t)row * N + col] = f2bf(acc[mi][ni][i] + bv);
                }
        }
    } else {
        #pragma unroll
        for (int ni = 0; ni < 4; ni++) {
            int col = n0 + wc * 64 + ni * 16 + c;
            float bv = bias[col];
            int hh = col >> 6, d = col & 63;
            #pragma unroll
            for (int mi = 0; mi < 4; mi++) {
                int row0 = m0 + wr * 64 + mi * 16 + g * 4;
                int bb = row0 >> 11, s = row0 & 2047;
                u32 lo = (u32)f2bf(acc[mi][ni][0] + bv) | ((u32)f2bf(acc[mi][ni][1] + bv) << 16);
                u32 hi = (u32)f2bf(acc[mi][ni][2] + bv) | ((u32)f2bf(acc[mi][ni][3] + bv) << 16);
                size_t idx = ((size_t)((bb * 16 + hh) * 64 + d)) * 2048 + s;
                *reinterpret_cast<uint2*>(Vt + idx) = make_uint2(lo, hi);
            }
        }
    }
}

// ---------------- output GEMM: C = A @ W^T + bias, fp32 out ----------------
__global__ __launch_bounds__(256) void k_gemm_f32(const u16* __restrict__ A, const u16* __restrict__ W,
                                                  const float* __restrict__ bias, float* __restrict__ Cout) {
    __shared__ __attribute__((aligned(16))) u16 Alds[128 * 32];
    __shared__ __attribute__((aligned(16))) u16 Blds[128 * 32];
    const int tid = threadIdx.x;
    const int w = tid >> 6, lane = tid & 63;
    const int wr = w >> 1, wc = w & 1;
    const int c = lane & 15, g = lane >> 4;
    const int m0 = blockIdx.y * 128, n0 = blockIdx.x * 128;
    const int K = 1024, N = 1024;

    floatx4 acc[4][4] = {};
    const int srow = lane >> 2;
    const int skc = (lane & 3) * 8;

    for (int k0 = 0; k0 < K; k0 += 32) {
        #pragma unroll
        for (int ch = 0; ch < 2; ch++) {
            int cc = w + ch * 4;
            const u16* ga = A + (size_t)(m0 + cc * 16 + srow) * K + k0 + skc;
            const u16* gb = W + (size_t)(n0 + cc * 16 + srow) * K + k0 + skc;
            __builtin_amdgcn_global_load_lds((AS1 void*)(ga), (AS3 void*)(Alds + cc * 512), 16, 0, 0);
            __builtin_amdgcn_global_load_lds((AS1 void*)(gb), (AS3 void*)(Blds + cc * 512), 16, 0, 0);
        }
        __syncthreads();
        bf16x8 af[4], bfr[4];
        #pragma unroll
        for (int mi = 0; mi < 4; mi++)
            af[mi] = *reinterpret_cast<const bf16x8*>(Alds + (wr * 64 + mi * 16 + c) * 32 + g * 8);
        #pragma unroll
        for (int ni = 0; ni < 4; ni++)
            bfr[ni] = *reinterpret_cast<const bf16x8*>(Blds + (wc * 64 + ni * 16 + c) * 32 + g * 8);
        #pragma unroll
        for (int mi = 0; mi < 4; mi++)
            #pragma unroll
            for (int ni = 0; ni < 4; ni++)
                acc[mi][ni] = __builtin_amdgcn_mfma_f32_16x16x32_bf16(af[mi], bfr[ni], acc[mi][ni], 0, 0, 0);
        __syncthreads();
    }

    #pragma unroll
    for (int ni = 0; ni < 4; ni++) {
        int col = n0 + wc * 64 + ni * 16 + c;
        float bv = bias[col];
        #pragma unroll
        for (int mi = 0; mi < 4; mi++)
            #pragma unroll
            for (int i = 0; i < 4; i++) {
                int row = m0 + wr * 64 + mi * 16 + g * 4 + i;
                Cout[(size_t)row * N + col] = acc[mi][ni][i] + bv;
            }
    }
}

// ---------------- Flash attention, causal, swapped-operand 32x32x16 structure.
// Placement-robust complementary q-block pairing: adjacent ids AND ids+256 complement.
// Q pre-scaled by 0.125*log2(e). Q,K bf16 [B][S][1024]; Vt bf16 [bh][64][S]; O bf16.
__global__ __launch_bounds__(256, 2) void k_attn(const u16* __restrict__ Q, const u16* __restrict__ Kg,
                                                 const u16* __restrict__ Vt, u16* __restrict__ O) {
    __shared__ __attribute__((aligned(16))) u16 Kl[2][64][64]; // [kv][d], 16B-blocks swizzled by row&7
    __shared__ __attribute__((aligned(16))) u16 Vl[2][64][64]; // [d][s], swizzled likewise

    const int tid = threadIdx.x;
    const int w = tid >> 6, lane = tid & 63;
    const int l31 = lane & 31, hi = lane >> 5;
    const int lr = lane >> 3, lb = (lane & 7) ^ (lr & 7);
    const int sw = l31 & 7; // read-side swizzle key

    // decode: bh = {b8, b7..b4}; j = (id>>1)&7; s = b0 ^ b8; qb = s ? 15-j : j.
    // adjacent ids complement; ids 256 apart complement -> per-CU work constant
    // under chunked OR round-robin placement.
    const int id = blockIdx.x;
    const int bh = ((id >> 8) << 4) | ((id >> 4) & 15);
    const int j = (id >> 1) & 7;
    const int s8 = (id ^ (id >> 8)) & 1;
    const int qb = s8 ? 15 - j : j;
    const int b = bh >> 4, h = bh & 15;
    const int q0b = qb * 128;
    const int wq0 = q0b + 32 * w;
    const int rowb = b * 2048, colb = h * 64;
    const u16* __restrict__ Kb = Kg + (size_t)rowb * 1024 + colb;
    const u16* __restrict__ Vb = Vt + (size_t)bh * 64 * 2048;
    const int ntb = 2 * qb + 2;
    const int wnt = (wq0 + 31) / 64 + 1;
    const int myq = wq0 + l31;

    // Q B-frags (4 d-steps of 16): qf[s][j] = Q[myq][s*16 + hi*8 + j]  (pre-scaled)
    bf16x8 qf[4];
    #pragma unroll
    for (int s = 0; s < 4; s++)
        qf[s] = *reinterpret_cast<const bf16x8*>(Q + (size_t)(rowb + myq) * 1024 + colb + s * 16 + hi * 8);

    float mreg = -1e30f, ls = 0.f;
    floatx16 acc0 = {}, acc1 = {}; // O^T: d rows 0..31 / 32..63, col = myq

    auto STAGE = [&](int bf, int t) {
        const int kv0s = t * 64;
        const u16* gk = Kb + (size_t)(kv0s + 16 * w + lr) * 1024 + lb * 8;
        __builtin_amdgcn_global_load_lds((AS1 void*)gk, (AS3 void*)&Kl[bf][16 * w][0], 16, 0, 0);
        __builtin_amdgcn_global_load_lds((AS1 void*)(gk + 8 * 1024), (AS3 void*)&Kl[bf][16 * w + 8][0], 16, 0, 0);
        const u16* gv = Vb + (size_t)(16 * w + lr) * 2048 + kv0s + lb * 8;
        __builtin_amdgcn_global_load_lds((AS1 void*)gv, (AS3 void*)&Vl[bf][16 * w][0], 16, 0, 0);
        __builtin_amdgcn_global_load_lds((AS1 void*)(gv + 8 * 2048), (AS3 void*)&Vl[bf][16 * w + 8][0], 16, 0, 0);
    };

    STAGE(0, 0);
    __syncthreads();

    for (int t = 0; t < ntb; t++) {
        const int bf = t & 1;
        const int kv0 = t * 64;
        if (t + 1 < ntb) STAGE(bf ^ 1, t + 1);

        if (t < wnt) {
            #pragma unroll
            for (int kb = 0; kb < 2; kb++) {
                const int kvb = kv0 + kb * 32;
                if (kvb <= wq0 + 31) { // wave-uniform
                    // S^T = K @ Q^T : 4 mfma over d
                    floatx16 st4 = {};
                    __builtin_amdgcn_s_setprio(1);
                    #pragma unroll
                    for (int s = 0; s < 4; s++) {
                        bf16x8 kf = *reinterpret_cast<const bf16x8*>(
                            &Kl[bf][kb * 32 + l31][(((s * 2 + hi) ^ sw) << 3)]);
                        st4 = __builtin_amdgcn_mfma_f32_32x32x16_bf16(kf, qf[s], st4, 0, 0, 0);
                    }
                    __builtin_amdgcn_s_setprio(0);

                    // causal mask; p[rr] = S[myq][kvb + (rr&3)+8*(rr>>2)+4*hi] (already scaled)
                    float p[16];
                    const bool diag = (kvb + 31 > wq0); // wave-uniform
                    #pragma unroll
                    for (int rr = 0; rr < 16; rr++) {
                        float sv = st4[rr];
                        if (diag) {
                            int kv = kvb + (rr & 3) + 8 * (rr >> 2) + 4 * hi;
                            if (kv > myq) sv = -1e30f;
                        }
                        p[rr] = sv;
                    }
                    // row max (in-register tree + lane^32 exchange)
                    float pm = fmaxf(
                        fmaxf(fmaxf(fmaxf(p[0], p[1]), fmaxf(p[2], p[3])),
                              fmaxf(fmaxf(p[4], p[5]), fmaxf(p[6], p[7]))),
                        fmaxf(fmaxf(fmaxf(p[8], p[9]), fmaxf(p[10], p[11])),
                              fmaxf(fmaxf(p[12], p[13]), fmaxf(p[14], p[15]))));
                    pm = fmaxf(pm, __shfl_xor(pm, 32));
                    if (__any(pm > mreg + 8.f)) { // defer-max (THR=8)
                        float mn = fmaxf(mreg, pm);
                        float corr = exp2f(mreg - mn);
                        mreg = mn;
                        ls *= corr;
                        acc0 *= corr;
                        acc1 *= corr;
                    }
                    // exp + row sum
                    #pragma unroll
                    for (int rr = 0; rr < 16; rr++) p[rr] = exp2f(p[rr] - mreg);
                    float sm = ((p[0] + p[1]) + (p[2] + p[3])) + ((p[4] + p[5]) + (p[6] + p[7]))
                             + ((p[8] + p[9]) + (p[10] + p[11])) + ((p[12] + p[13]) + (p[14] + p[15]));
                    sm += __shfl_xor(sm, 32);
                    ls += sm;

                    // P^T B-frags: step0 from p[0..7], step1 from p[8..15]
                    union { u32 u[4]; bf16x8 v; } f0, f1;
                    {
                        u32 a0 = cvtpk(p[0], p[1]), b0 = cvtpk(p[4], p[5]);
                        u32 c0 = cvtpk(p[2], p[3]), d0 = cvtpk(p[6], p[7]);
                        plswap(a0, b0); plswap(c0, d0);
                        f0.u[0] = a0; f0.u[1] = c0; f0.u[2] = b0; f0.u[3] = d0;
                        u32 e1 = cvtpk(p[8], p[9]),  g1 = cvtpk(p[12], p[13]);
                        u32 h1 = cvtpk(p[10], p[11]), i1 = cvtpk(p[14], p[15]);
                        plswap(e1, g1); plswap(h1, i1);
                        f1.u[0] = e1; f1.u[1] = h1; f1.u[2] = g1; f1.u[3] = i1;
                    }
                    // O^T += V^T @ P^T : 2 k-steps x 2 d-tiles
                    __builtin_amdgcn_s_setprio(1);
                    #pragma unroll
                    for (int s = 0; s < 2; s++) {
                        const int blk = (kb * 4 + s * 2 + hi) ^ sw;
                        bf16x8 v0 = *reinterpret_cast<const bf16x8*>(&Vl[bf][l31][blk << 3]);
                        bf16x8 v1 = *reinterpret_cast<const bf16x8*>(&Vl[bf][32 + l31][blk << 3]);
                        const bf16x8 pf = (s == 0) ? f0.v : f1.v;
                        acc0 = __builtin_amdgcn_mfma_f32_32x32x16_bf16(v0, pf, acc0, 0, 0, 0);
                        acc1 = __builtin_amdgcn_mfma_f32_32x32x16_bf16(v1, pf, acc1, 0, 0, 0);
                    }
                    __builtin_amdgcn_s_setprio(0);
                }
            }
        }
        __syncthreads();
    }

    // epilogue: O[rowb+myq][colb + d], d = 32*db + 8*g4 + 4*hi + (0..3)
    const float inv = 1.f / ls;
    u16* __restrict__ Orow = O + (size_t)(rowb + myq) * 1024 + colb;
    #pragma unroll
    for (int db = 0; db < 2; db++) {
        const floatx16& a = db ? acc1 : acc0;
        #pragma unroll
        for (int g4 = 0; g4 < 4; g4++) {
            u32 lo = cvtpk(a[g4 * 4 + 0] * inv, a[g4 * 4 + 1] * inv);
            u32 hh = cvtpk(a[g4 * 4 + 2] * inv, a[g4 * 4 + 3] * inv);
            *reinterpret_cast<uint2*>(Orow + db * 32 + g4 * 8 + hi * 4) = make_uint2(lo, hh);
        }
    }
}

extern "C" void kernel_launch(void* const* d_in, const int* in_sizes, int n_in,
                              void* d_out, int out_size, void* d_ws, size_t ws_size,
                              hipStream_t stream) {
    const float* x  = (const float*)d_in[0];
    const float* wq = (const float*)d_in[1];
    const float* bq = (const float*)d_in[2];
    const float* wk = (const float*)d_in[3];
    const float* bk = (const float*)d_in[4];
    const float* wv = (const float*)d_in[5];
    const float* bv = (const float*)d_in[6];
    const float* wo = (const float*)d_in[7];
    const float* bo = (const float*)d_in[8];

    char* ws = (char*)d_ws;
    u16* xb  = (u16*)(ws);                      // 8 MiB [4096][1024]
    u16* wqb = (u16*)(ws + (8ull  << 20));      // 2 MiB each
    u16* wkb = (u16*)(ws + (10ull << 20));
    u16* wvb = (u16*)(ws + (12ull << 20));
    u16* wob = (u16*)(ws + (14ull << 20));
    u16* qg  = (u16*)(ws + (16ull << 20));      // 8 MiB
    u16* kg  = (u16*)(ws + (24ull << 20));      // 8 MiB
    u16* vt  = (u16*)(ws + (32ull << 20));      // 8 MiB [32][64][2048]
    u16* og  = (u16*)(ws + (40ull << 20));      // 8 MiB
    float* ct = (float*)(ws + (48ull << 20));   // 512 KiB
    float* st = (float*)(ws + (49ull << 20));   // 512 KiB

    k_prep<<<8704, 256, 0, stream>>>(x, wq, wk, wv, wo, xb, wqb, wkb, wvb, wob, ct, st);

    dim3 gq(8, 32, 3);
    k_gemm_qkv<<<gq, 256, 0, stream>>>(xb, wqb, wkb, wvb, bq, bk, bv, qg, kg, vt);

    k_rope_apply<<<8192, 256, 0, stream>>>(qg, kg, ct, st);

    k_attn<<<512, 256, 0, stream>>>(qg, kg, vt, og);

    k_gemm_f32<<<dim3(8, 32), 256, 0, stream>>>(og, wob, bo, (float*)d_out);
}